// Round 5
// baseline (329.114 us; speedup 1.0000x reference)
//
#include <hip/hip_runtime.h>
#include <cstdint>
#include <cstddef>

#define T_TOK 8192
#define DDIM 1024
#define FDIM 2048
#define NEXP 8

typedef _Float16 f16x8 __attribute__((ext_vector_type(8)));
typedef _Float16 f16x4 __attribute__((ext_vector_type(4)));
typedef float f32x4 __attribute__((ext_vector_type(4)));

__device__ __forceinline__ void gl_lds16(const void* g, void* s) {
  __builtin_amdgcn_global_load_lds(
      (const __attribute__((address_space(1))) void*)g,
      (__attribute__((address_space(3))) void*)s, 16, 0, 0);
}

// ---------------- gating (fp64 accumulate, no atomics) ----------------
__global__ __launch_bounds__(256) void k_gate(
    const float* __restrict__ x, const float* __restrict__ gW,
    const float* __restrict__ gb, int* __restrict__ idx,
    float* __restrict__ wgt) {
  int wid = threadIdx.x >> 6, lane = threadIdx.x & 63;
  int wave = blockIdx.x * 4 + wid;
  int t0 = wave * 2;

  double acc[2][NEXP];
#pragma unroll
  for (int tk = 0; tk < 2; ++tk)
#pragma unroll
    for (int e = 0; e < NEXP; ++e) acc[tk][e] = 0.0;

#pragma unroll
  for (int ch = 0; ch < 4; ++ch) {
    int dbase = ch * 256 + 4 * lane;
    const f32x4* wp = (const f32x4*)(gW + (size_t)dbase * NEXP);
    f32x4 wv[8];
#pragma unroll
    for (int i = 0; i < 8; ++i) wv[i] = wp[i];
#pragma unroll
    for (int tk = 0; tk < 2; ++tk) {
      f32x4 xv = *(const f32x4*)(x + (size_t)(t0 + tk) * DDIM + dbase);
#pragma unroll
      for (int j = 0; j < 4; ++j) {
        double xd = (double)xv[j];
#pragma unroll
        for (int e = 0; e < NEXP; ++e)
          acc[tk][e] += xd * (double)wv[2 * j + (e >> 2)][e & 3];
      }
    }
  }

#pragma unroll
  for (int off = 32; off > 0; off >>= 1) {
#pragma unroll
    for (int tk = 0; tk < 2; ++tk)
#pragma unroll
      for (int e = 0; e < NEXP; ++e)
        acc[tk][e] += __shfl_xor(acc[tk][e], off, 64);
  }
  if (lane == 0) {
#pragma unroll
    for (int tk = 0; tk < 2; ++tk) {
      double mx = -1e300; int am = 0;
#pragma unroll
      for (int e = 0; e < NEXP; ++e) {
        acc[tk][e] += (double)gb[e];
        if (acc[tk][e] > mx) { mx = acc[tk][e]; am = e; }
      }
      double s = 0.0;
#pragma unroll
      for (int e = 0; e < NEXP; ++e) s += exp(acc[tk][e] - mx);
      idx[t0 + tk] = am;
      wgt[t0 + tk] = (float)(1.0 / s);
    }
  }
}

// ---------------- routing: counts/offsets/loss + stable rank scatter ------
__global__ __launch_bounds__(1024) void k_route(
    const int* __restrict__ idx, const float* __restrict__ wgt,
    int* __restrict__ perm, int* __restrict__ counts_out,
    int* __restrict__ offs_out, float* __restrict__ loss_out) {
  __shared__ int cnt_ws[16][NEXP];
  __shared__ float sc_ws[16][NEXP];
  __shared__ int wprefix[16][NEXP];
  __shared__ int base[NEXP];

  int tid = threadIdx.x, w = tid >> 6, lane = tid & 63;

  int c_e[NEXP];
  float s_e[NEXP];
#pragma unroll
  for (int e = 0; e < NEXP; ++e) { c_e[e] = 0; s_e[e] = 0.f; }
  for (int c = 0; c < 8; ++c) {
    int t = c * 1024 + tid;
    int my = idx[t];
    float mw = wgt[t];
#pragma unroll
    for (int e = 0; e < NEXP; ++e) {
      unsigned long long m = __ballot(my == e);
      if (lane == 0) c_e[e] += (int)__popcll(m);
      s_e[e] += (my == e) ? mw : 0.f;
    }
  }
#pragma unroll
  for (int off = 32; off > 0; off >>= 1) {
#pragma unroll
    for (int e = 0; e < NEXP; ++e) s_e[e] += __shfl_xor(s_e[e], off, 64);
  }
  if (lane == 0) {
#pragma unroll
    for (int e = 0; e < NEXP; ++e) { cnt_ws[w][e] = c_e[e]; sc_ws[w][e] = s_e[e]; }
  }
  __syncthreads();
  if (tid == 0) {
    int tot[NEXP]; float sct[NEXP];
#pragma unroll
    for (int e = 0; e < NEXP; ++e) { tot[e] = 0; sct[e] = 0.f; }
    for (int ww = 0; ww < 16; ++ww)
#pragma unroll
      for (int e = 0; e < NEXP; ++e) { tot[e] += cnt_ws[ww][e]; sct[e] += sc_ws[ww][e]; }
    int off = 0; float loss = 0.f;
#pragma unroll
    for (int e = 0; e < NEXP; ++e) {
      offs_out[e] = off; counts_out[e] = tot[e];
      base[e] = off;
      off += tot[e];
      float usage = sct[e] / ((float)tot[e] + 1e-8f);
      float d = usage - (1.0f / NEXP);
      loss += d * d;
    }
    loss_out[0] = loss;
  }
  __syncthreads();

  unsigned long long lt_mask = ((unsigned long long)1 << lane) - 1ull;
  for (int c = 0; c < 8; ++c) {
    int t = c * 1024 + tid;
    int my = idx[t];
    int rank_w = 0;
    int wcnt[NEXP];
#pragma unroll
    for (int e = 0; e < NEXP; ++e) {
      unsigned long long m = __ballot(my == e);
      if (my == e) rank_w = (int)__popcll(m & lt_mask);
      wcnt[e] = (int)__popcll(m);
    }
    if (lane == 0) {
#pragma unroll
      for (int e = 0; e < NEXP; ++e) cnt_ws[w][e] = wcnt[e];
    }
    __syncthreads();
    if (tid < 128) {
      int ww = tid >> 3, e = tid & 7;
      int p = 0;
      for (int w2 = 0; w2 < 16; ++w2) if (w2 < ww) p += cnt_ws[w2][e];
      wprefix[ww][e] = p;
    }
    __syncthreads();
    int pos = base[my] + wprefix[w][my] + rank_w;
    perm[pos] = t;
    __syncthreads();
    if (tid < 8) base[tid] += wprefix[15][tid] + cnt_ws[15][tid];
    __syncthreads();
  }
}

// ---------------- transpose + fp32->fp16 convert ----------------
__global__ __launch_bounds__(256) void k_transpose_cvt(
    const float* __restrict__ src, _Float16* __restrict__ dst, int R, int C) {
  __shared__ _Float16 tile[32][33];
  int tx = threadIdx.x & 31, ty = threadIdx.x >> 5;
  size_t base = (size_t)blockIdx.z * (size_t)R * (size_t)C;
  int c0 = blockIdx.x * 32, r0 = blockIdx.y * 32;
  const float* s = src + base;
  _Float16* d = dst + base;
#pragma unroll
  for (int i = 0; i < 32; i += 8)
    tile[ty + i][tx] = (_Float16)s[(size_t)(r0 + ty + i) * C + c0 + tx];
  __syncthreads();
#pragma unroll
  for (int i = 0; i < 32; i += 8)
    d[(size_t)(c0 + ty + i) * R + r0 + tx] = tile[tx][ty + i];
}

// ---------------- gather tokens + fp32->fp16 ----------------
__global__ __launch_bounds__(256) void k_gather_cvt(
    const float* __restrict__ x, const int* __restrict__ perm,
    _Float16* __restrict__ Xg) {
  int p = blockIdx.x;
  int t = perm[p];
  const float4* srow = (const float4*)(x + (size_t)t * DDIM);
  f16x4* drow = (f16x4*)(Xg + (size_t)p * DDIM);
  float4 v = srow[threadIdx.x];
  f16x4 h = { (_Float16)v.x, (_Float16)v.y, (_Float16)v.z, (_Float16)v.w };
  drow[threadIdx.x] = h;
}

// ---------------- GEMM1 + GLU epilogue (BK=64, XOR-swizzled LDS) ---------
__global__ __launch_bounds__(256) void k_gemm1_glu(
    const _Float16* __restrict__ Xg, const _Float16* __restrict__ Wt,
    const float* __restrict__ fcb, const int* __restrict__ offs,
    const int* __restrict__ counts, _Float16* __restrict__ G) {
  int e = blockIdx.y >> 6;
  int m0 = (blockIdx.y & 63) * 128;
  int n_e = counts[e];
  if (m0 >= n_e) return;
  int seg = offs[e];
  int n0 = blockIdx.x * 64;

  __shared__ __align__(16) _Float16 As[128][64];   // 16 KB
  __shared__ __align__(16) _Float16 B1s[64][64];   // 8 KB
  __shared__ __align__(16) _Float16 B2s[64][64];   // 8 KB

  int tid = threadIdx.x;
  int wid = tid >> 6, lane = tid & 63;
  int wm = wid >> 1, wn = wid & 1;

  const _Float16* We = Wt + (size_t)e * (4096ull * 1024ull);
  const float* fcbe = fcb + e * 4096;

  // staging: thread -> (row = tid>>3 within 32-row slab, dest chunk = tid&7)
  // source chunk pre-swizzled so LDS[r][c^(r&7)] = global[r][c]
  int srow = tid >> 3;
  int scol = ((tid & 7) ^ (srow & 7)) * 8;
  const _Float16* gA[4]; _Float16* lA[4];
#pragma unroll
  for (int s = 0; s < 4; ++s) {
    int r = min(seg + m0 + s * 32 + srow, T_TOK - 1);
    gA[s] = Xg + (size_t)r * DDIM + scol;
    lA[s] = &As[0][0] + s * 2048 + tid * 8;
  }
  const _Float16* gB1[2]; const _Float16* gB2[2]; _Float16* lB1[2]; _Float16* lB2[2];
#pragma unroll
  for (int s = 0; s < 2; ++s) {
    gB1[s] = We + (size_t)(n0 + s * 32 + srow) * DDIM + scol;
    gB2[s] = We + (size_t)(2048 + n0 + s * 32 + srow) * DDIM + scol;
    lB1[s] = &B1s[0][0] + s * 2048 + tid * 8;
    lB2[s] = &B2s[0][0] + s * 2048 + tid * 8;
  }

  f32x4 acc1[4][2], acc2[4][2];
#pragma unroll
  for (int a = 0; a < 4; ++a)
#pragma unroll
    for (int b = 0; b < 2; ++b) {
      acc1[a][b] = (f32x4){0.f, 0.f, 0.f, 0.f};
      acc2[a][b] = (f32x4){0.f, 0.f, 0.f, 0.f};
    }

  int lr = lane & 15;
  int g = lane >> 4;
  int arow[4], brow[2];
#pragma unroll
  for (int mf = 0; mf < 4; ++mf) arow[mf] = wm * 64 + mf * 16 + lr;
#pragma unroll
  for (int nf = 0; nf < 2; ++nf) brow[nf] = wn * 32 + nf * 16 + lr;
  int coff0 = ((0 * 4 + g) ^ (lr & 7)) * 16;
  int coff1 = ((1 * 4 + g) ^ (lr & 7)) * 16;

  for (int k0 = 0; k0 < DDIM; k0 += 64) {
#pragma unroll
    for (int s = 0; s < 4; ++s) gl_lds16(gA[s] + k0, lA[s]);
#pragma unroll
    for (int s = 0; s < 2; ++s) {
      gl_lds16(gB1[s] + k0, lB1[s]);
      gl_lds16(gB2[s] + k0, lB2[s]);
    }
    __syncthreads();
#pragma unroll
    for (int kk = 0; kk < 2; ++kk) {
      int coff = kk ? coff1 : coff0;
      f16x8 a[4], b1[2], b2[2];
#pragma unroll
      for (int mf = 0; mf < 4; ++mf)
        a[mf] = *(const f16x8*)((const char*)&As[0][0] + arow[mf] * 128 + coff);
#pragma unroll
      for (int nf = 0; nf < 2; ++nf) {
        b1[nf] = *(const f16x8*)((const char*)&B1s[0][0] + brow[nf] * 128 + coff);
        b2[nf] = *(const f16x8*)((const char*)&B2s[0][0] + brow[nf] * 128 + coff);
      }
#pragma unroll
      for (int mf = 0; mf < 4; ++mf)
#pragma unroll
        for (int nf = 0; nf < 2; ++nf) {
          acc1[mf][nf] = __builtin_amdgcn_mfma_f32_16x16x32_f16(a[mf], b1[nf], acc1[mf][nf], 0, 0, 0);
          acc2[mf][nf] = __builtin_amdgcn_mfma_f32_16x16x32_f16(a[mf], b2[nf], acc2[mf][nf], 0, 0, 0);
        }
    }
    __syncthreads();
  }

  int lk4 = g * 4;
#pragma unroll
  for (int mf = 0; mf < 4; ++mf) {
#pragma unroll
    for (int i = 0; i < 4; ++i) {
      int pl = m0 + wm * 64 + mf * 16 + lk4 + i;
      if (pl >= n_e) continue;
      size_t grow = (size_t)(seg + pl) * FDIM;
#pragma unroll
      for (int nf = 0; nf < 2; ++nf) {
        int col = n0 + wn * 32 + nf * 16 + lr;
        float x1 = acc1[mf][nf][i] + fcbe[col];
        float x2v = acc2[mf][nf][i] + fcbe[2048 + col];
        float gg = x1 * x2v * 0.5f * (1.0f + erff(x2v * 0.70710678118654752f));
        G[grow + col] = (_Float16)gg;
      }
    }
  }
}

// ---------------- GEMM2 + bias + weight scale + scatter (BK=64, swz) -----
__global__ __launch_bounds__(256) void k_gemm2_out(
    const _Float16* __restrict__ G, const _Float16* __restrict__ Vt,
    const float* __restrict__ ob, const int* __restrict__ offs,
    const int* __restrict__ counts, const int* __restrict__ perm,
    const float* __restrict__ wgt, float* __restrict__ out) {
  int e = blockIdx.y >> 6;
  int m0 = (blockIdx.y & 63) * 128;
  int n_e = counts[e];
  if (m0 >= n_e) return;
  int seg = offs[e];
  int n0 = blockIdx.x * 128;

  __shared__ __align__(16) _Float16 As[128][64];   // 16 KB
  __shared__ __align__(16) _Float16 Bs[128][64];   // 16 KB

  int tid = threadIdx.x, wid = tid >> 6, lane = tid & 63;
  int wm = wid >> 1, wn = wid & 1;
  const _Float16* Ve = Vt + (size_t)e * (1024ull * 2048ull);
  const float* obe = ob + e * 1024;

  int srow = tid >> 3;
  int scol = ((tid & 7) ^ (srow & 7)) * 8;
  const _Float16* gA[4]; const _Float16* gB[4]; _Float16* lA[4]; _Float16* lB[4];
#pragma unroll
  for (int s = 0; s < 4; ++s) {
    int r = min(seg + m0 + s * 32 + srow, T_TOK - 1);
    gA[s] = G + (size_t)r * FDIM + scol;
    gB[s] = Ve + (size_t)(n0 + s * 32 + srow) * FDIM + scol;
    lA[s] = &As[0][0] + s * 2048 + tid * 8;
    lB[s] = &Bs[0][0] + s * 2048 + tid * 8;
  }

  f32x4 acc[4][4];
#pragma unroll
  for (int a = 0; a < 4; ++a)
#pragma unroll
    for (int b = 0; b < 4; ++b) acc[a][b] = (f32x4){0.f, 0.f, 0.f, 0.f};

  int lr = lane & 15;
  int g = lane >> 4;
  int arow[4], brow[4];
#pragma unroll
  for (int mf = 0; mf < 4; ++mf) arow[mf] = wm * 64 + mf * 16 + lr;
#pragma unroll
  for (int nf = 0; nf < 4; ++nf) brow[nf] = wn * 64 + nf * 16 + lr;
  int coff0 = ((0 * 4 + g) ^ (lr & 7)) * 16;
  int coff1 = ((1 * 4 + g) ^ (lr & 7)) * 16;

  for (int k0 = 0; k0 < FDIM; k0 += 64) {
#pragma unroll
    for (int s = 0; s < 4; ++s) {
      gl_lds16(gA[s] + k0, lA[s]);
      gl_lds16(gB[s] + k0, lB[s]);
    }
    __syncthreads();
#pragma unroll
    for (int kk = 0; kk < 2; ++kk) {
      int coff = kk ? coff1 : coff0;
      f16x8 a[4], b[4];
#pragma unroll
      for (int mf = 0; mf < 4; ++mf)
        a[mf] = *(const f16x8*)((const char*)&As[0][0] + arow[mf] * 128 + coff);
#pragma unroll
      for (int nf = 0; nf < 4; ++nf)
        b[nf] = *(const f16x8*)((const char*)&Bs[0][0] + brow[nf] * 128 + coff);
#pragma unroll
      for (int mf = 0; mf < 4; ++mf)
#pragma unroll
        for (int nf = 0; nf < 4; ++nf)
          acc[mf][nf] = __builtin_amdgcn_mfma_f32_16x16x32_f16(a[mf], b[nf], acc[mf][nf], 0, 0, 0);
    }
    __syncthreads();
  }

  int lk4 = g * 4;
#pragma unroll
  for (int mf = 0; mf < 4; ++mf) {
#pragma unroll
    for (int i = 0; i < 4; ++i) {
      int pl = m0 + wm * 64 + mf * 16 + lk4 + i;
      if (pl >= n_e) continue;
      int p = seg + pl;
      int t = perm[p];
      float wv = wgt[t];
      float* orow = out + (size_t)t * DDIM;
#pragma unroll
      for (int nf = 0; nf < 4; ++nf) {
        int col = n0 + wn * 64 + nf * 16 + lr;
        orow[col] = (acc[mf][nf][i] + obe[col]) * wv;
      }
    }
  }
}

extern "C" void kernel_launch(void* const* d_in, const int* in_sizes, int n_in,
                              void* d_out, int out_size, void* d_ws, size_t ws_size,
                              hipStream_t stream) {
  const float* x   = (const float*)d_in[0];
  const float* gW  = (const float*)d_in[1];
  const float* gb  = (const float*)d_in[2];
  const float* fcW = (const float*)d_in[3];
  const float* fcb = (const float*)d_in[4];
  const float* oW  = (const float*)d_in[5];
  const float* ob  = (const float*)d_in[6];
  float* out = (float*)d_out;

  char* p = (char*)d_ws;
  _Float16* fcWt  = (_Float16*)p; p += (size_t)NEXP * 4096 * 1024 * 2;
  _Float16* outWt = (_Float16*)p; p += (size_t)NEXP * 1024 * 2048 * 2;
  _Float16* Xg    = (_Float16*)p; p += (size_t)T_TOK * DDIM * 2;
  _Float16* G     = (_Float16*)p; p += (size_t)T_TOK * FDIM * 2;
  int*   idx     = (int*)p;   p += T_TOK * 4;
  float* wgt     = (float*)p; p += T_TOK * 4;
  int*   perm    = (int*)p;   p += T_TOK * 4;
  int*   counts  = (int*)p;   p += 64;
  int*   offs    = (int*)p;   p += 64;

  k_gate<<<T_TOK / 8, 256, 0, stream>>>(x, gW, gb, idx, wgt);
  k_route<<<1, 1024, 0, stream>>>(idx, wgt, perm, counts, offs,
                                  out + (size_t)T_TOK * DDIM);
  k_transpose_cvt<<<dim3(4096 / 32, 1024 / 32, NEXP), 256, 0, stream>>>(fcW, fcWt, 1024, 4096);
  k_transpose_cvt<<<dim3(1024 / 32, 2048 / 32, NEXP), 256, 0, stream>>>(oW, outWt, 2048, 1024);
  k_gather_cvt<<<T_TOK, 256, 0, stream>>>(x, perm, Xg);
  k_gemm1_glu<<<dim3(2048 / 64, NEXP * 64), 256, 0, stream>>>(Xg, fcWt, fcb, offs, counts, G);
  k_gemm2_out<<<dim3(1024 / 128, NEXP * 64), 256, 0, stream>>>(G, outWt, ob, offs, counts, perm, wgt, out);
}

// Round 6
// 316.863 us; speedup vs baseline: 1.0387x; 1.0387x over previous
//
#include <hip/hip_runtime.h>
#include <cstdint>
#include <cstddef>

#define T_TOK 8192
#define DDIM 1024
#define FDIM 2048
#define NEXP 8

typedef _Float16 f16x8 __attribute__((ext_vector_type(8)));
typedef _Float16 f16x4 __attribute__((ext_vector_type(4)));
typedef float f32x4 __attribute__((ext_vector_type(4)));

__device__ __forceinline__ void gl_lds16(const void* g, void* s) {
  __builtin_amdgcn_global_load_lds(
      (const __attribute__((address_space(1))) void*)g,
      (__attribute__((address_space(3))) void*)s, 16, 0, 0);
}

// ---------------- gating (fp64 accumulate, no atomics) + fp16 convert ----
// One wave per 2 tokens; also emits Xh[t] = fp16(x[t]) (unpermuted).
__global__ __launch_bounds__(256) void k_gate(
    const float* __restrict__ x, const float* __restrict__ gW,
    const float* __restrict__ gb, int* __restrict__ idx,
    float* __restrict__ wgt, _Float16* __restrict__ Xh) {
  int wid = threadIdx.x >> 6, lane = threadIdx.x & 63;
  int wave = blockIdx.x * 4 + wid;
  int t0 = wave * 2;

  double acc[2][NEXP];
#pragma unroll
  for (int tk = 0; tk < 2; ++tk)
#pragma unroll
    for (int e = 0; e < NEXP; ++e) acc[tk][e] = 0.0;

#pragma unroll
  for (int ch = 0; ch < 4; ++ch) {
    int dbase = ch * 256 + 4 * lane;
    const f32x4* wp = (const f32x4*)(gW + (size_t)dbase * NEXP);
    f32x4 wv[8];
#pragma unroll
    for (int i = 0; i < 8; ++i) wv[i] = wp[i];
#pragma unroll
    for (int tk = 0; tk < 2; ++tk) {
      f32x4 xv = *(const f32x4*)(x + (size_t)(t0 + tk) * DDIM + dbase);
      f16x4 h = { (_Float16)xv[0], (_Float16)xv[1], (_Float16)xv[2], (_Float16)xv[3] };
      *(f16x4*)(Xh + (size_t)(t0 + tk) * DDIM + dbase) = h;
#pragma unroll
      for (int j = 0; j < 4; ++j) {
        double xd = (double)xv[j];
#pragma unroll
        for (int e = 0; e < NEXP; ++e)
          acc[tk][e] += xd * (double)wv[2 * j + (e >> 2)][e & 3];
      }
    }
  }

#pragma unroll
  for (int off = 32; off > 0; off >>= 1) {
#pragma unroll
    for (int tk = 0; tk < 2; ++tk)
#pragma unroll
      for (int e = 0; e < NEXP; ++e)
        acc[tk][e] += __shfl_xor(acc[tk][e], off, 64);
  }
  if (lane == 0) {
#pragma unroll
    for (int tk = 0; tk < 2; ++tk) {
      double mx = -1e300; int am = 0;
#pragma unroll
      for (int e = 0; e < NEXP; ++e) {
        acc[tk][e] += (double)gb[e];
        if (acc[tk][e] > mx) { mx = acc[tk][e]; am = e; }
      }
      double s = 0.0;
#pragma unroll
      for (int e = 0; e < NEXP; ++e) s += exp(acc[tk][e] - mx);
      idx[t0 + tk] = am;
      wgt[t0 + tk] = (float)(1.0 / s);
    }
  }
}

// ---------------- routing: counts/offsets/loss + stable rank scatter ------
__global__ __launch_bounds__(1024) void k_route(
    const int* __restrict__ idx, const float* __restrict__ wgt,
    int* __restrict__ perm, int* __restrict__ counts_out,
    int* __restrict__ offs_out, float* __restrict__ loss_out) {
  __shared__ int cnt_ws[16][NEXP];
  __shared__ float sc_ws[16][NEXP];
  __shared__ int wprefix[16][NEXP];
  __shared__ int base[NEXP];

  int tid = threadIdx.x, w = tid >> 6, lane = tid & 63;

  int c_e[NEXP];
  float s_e[NEXP];
#pragma unroll
  for (int e = 0; e < NEXP; ++e) { c_e[e] = 0; s_e[e] = 0.f; }
  for (int c = 0; c < 8; ++c) {
    int t = c * 1024 + tid;
    int my = idx[t];
    float mw = wgt[t];
#pragma unroll
    for (int e = 0; e < NEXP; ++e) {
      unsigned long long m = __ballot(my == e);
      if (lane == 0) c_e[e] += (int)__popcll(m);
      s_e[e] += (my == e) ? mw : 0.f;
    }
  }
#pragma unroll
  for (int off = 32; off > 0; off >>= 1) {
#pragma unroll
    for (int e = 0; e < NEXP; ++e) s_e[e] += __shfl_xor(s_e[e], off, 64);
  }
  if (lane == 0) {
#pragma unroll
    for (int e = 0; e < NEXP; ++e) { cnt_ws[w][e] = c_e[e]; sc_ws[w][e] = s_e[e]; }
  }
  __syncthreads();
  if (tid == 0) {
    int tot[NEXP]; float sct[NEXP];
#pragma unroll
    for (int e = 0; e < NEXP; ++e) { tot[e] = 0; sct[e] = 0.f; }
    for (int ww = 0; ww < 16; ++ww)
#pragma unroll
      for (int e = 0; e < NEXP; ++e) { tot[e] += cnt_ws[ww][e]; sct[e] += sc_ws[ww][e]; }
    int off = 0; float loss = 0.f;
#pragma unroll
    for (int e = 0; e < NEXP; ++e) {
      offs_out[e] = off; counts_out[e] = tot[e];
      base[e] = off;
      off += tot[e];
      float usage = sct[e] / ((float)tot[e] + 1e-8f);
      float d = usage - (1.0f / NEXP);
      loss += d * d;
    }
    loss_out[0] = loss;
  }
  __syncthreads();

  unsigned long long lt_mask = ((unsigned long long)1 << lane) - 1ull;
  for (int c = 0; c < 8; ++c) {
    int t = c * 1024 + tid;
    int my = idx[t];
    int rank_w = 0;
    int wcnt[NEXP];
#pragma unroll
    for (int e = 0; e < NEXP; ++e) {
      unsigned long long m = __ballot(my == e);
      if (my == e) rank_w = (int)__popcll(m & lt_mask);
      wcnt[e] = (int)__popcll(m);
    }
    if (lane == 0) {
#pragma unroll
      for (int e = 0; e < NEXP; ++e) cnt_ws[w][e] = wcnt[e];
    }
    __syncthreads();
    if (tid < 128) {
      int ww = tid >> 3, e = tid & 7;
      int p = 0;
      for (int w2 = 0; w2 < 16; ++w2) if (w2 < ww) p += cnt_ws[w2][e];
      wprefix[ww][e] = p;
    }
    __syncthreads();
    int pos = base[my] + wprefix[w][my] + rank_w;
    perm[pos] = t;
    __syncthreads();
    if (tid < 8) base[tid] += wprefix[15][tid] + cnt_ws[15][tid];
    __syncthreads();
  }
}

// ---------------- transpose + fp32->fp16 convert ----------------
__global__ __launch_bounds__(256) void k_transpose_cvt(
    const float* __restrict__ src, _Float16* __restrict__ dst, int R, int C) {
  __shared__ _Float16 tile[32][33];
  int tx = threadIdx.x & 31, ty = threadIdx.x >> 5;
  size_t base = (size_t)blockIdx.z * (size_t)R * (size_t)C;
  int c0 = blockIdx.x * 32, r0 = blockIdx.y * 32;
  const float* s = src + base;
  _Float16* d = dst + base;
#pragma unroll
  for (int i = 0; i < 32; i += 8)
    tile[ty + i][tx] = (_Float16)s[(size_t)(r0 + ty + i) * C + c0 + tx];
  __syncthreads();
#pragma unroll
  for (int i = 0; i < 32; i += 8)
    d[(size_t)(c0 + ty + i) * R + r0 + tx] = tile[tx][ty + i];
}

// ---------------- GEMM1 + GLU (BK=32, 2-way swizzle, prefetch dbuf) ------
__global__ __launch_bounds__(256) void k_gemm1_glu(
    const _Float16* __restrict__ Xh, const _Float16* __restrict__ Wt,
    const float* __restrict__ fcb, const int* __restrict__ offs,
    const int* __restrict__ counts, const int* __restrict__ perm,
    _Float16* __restrict__ G) {
  int e = blockIdx.y >> 6;
  int m0 = (blockIdx.y & 63) * 128;
  int n_e = counts[e];
  if (m0 >= n_e) return;
  int seg = offs[e];
  int n0 = blockIdx.x * 64;

  __shared__ __align__(16) _Float16 As[2][128][32];   // 16 KB
  __shared__ __align__(16) _Float16 B1s[2][64][32];   //  8 KB
  __shared__ __align__(16) _Float16 B2s[2][64][32];   //  8 KB

  int tid = threadIdx.x, wid = tid >> 6, lane = tid & 63;
  int wm = wid >> 1, wn = wid & 1;

  const _Float16* We = Wt + (size_t)e * (4096ull * 1024ull);
  const float* fcbe = fcb + e * 4096;

  // staging map: dest row = tid>>2 (64-row slab), dest chunk = tid&3
  // source chunk = dest_chunk ^ ((row>>1)&3)  [2-way-free swizzle]
  int srow = tid >> 2;
  int scol = ((tid & 3) ^ ((tid >> 3) & 3)) * 8;
  const _Float16* gA[2];
#pragma unroll
  for (int s = 0; s < 2; ++s) {
    int rowp = min(seg + m0 + s * 64 + srow, T_TOK - 1);
    gA[s] = Xh + (size_t)perm[rowp] * DDIM + scol;
  }
  const _Float16* gB1 = We + (size_t)(n0 + srow) * DDIM + scol;
  const _Float16* gB2 = We + (size_t)(2048 + n0 + srow) * DDIM + scol;

  f32x4 acc1[4][2], acc2[4][2];
#pragma unroll
  for (int a = 0; a < 4; ++a)
#pragma unroll
    for (int b = 0; b < 2; ++b) {
      acc1[a][b] = (f32x4){0.f, 0.f, 0.f, 0.f};
      acc2[a][b] = (f32x4){0.f, 0.f, 0.f, 0.f};
    }

  int lr = lane & 15, g = lane >> 4;
  int aoff[4], boff[2];
#pragma unroll
  for (int mf = 0; mf < 4; ++mf) {
    int r = wm * 64 + mf * 16 + lr;
    aoff[mf] = r * 64 + ((g ^ ((r >> 1) & 3)) * 16);
  }
#pragma unroll
  for (int nf = 0; nf < 2; ++nf) {
    int r = wn * 32 + nf * 16 + lr;
    boff[nf] = r * 64 + ((g ^ ((r >> 1) & 3)) * 16);
  }

#define G1_STAGE(buf, kt)                                             \
  do {                                                                 \
    int k0_ = (kt) * 32;                                               \
    gl_lds16(gA[0] + k0_, &As[(buf)][0][0] + tid * 8);                 \
    gl_lds16(gA[1] + k0_, &As[(buf)][0][0] + 2048 + tid * 8);          \
    gl_lds16(gB1 + k0_, &B1s[(buf)][0][0] + tid * 8);                  \
    gl_lds16(gB2 + k0_, &B2s[(buf)][0][0] + tid * 8);                  \
  } while (0)

#define G1_COMPUTE(buf)                                                \
  do {                                                                 \
    const char* pA = (const char*)&As[(buf)][0][0];                    \
    const char* pB1 = (const char*)&B1s[(buf)][0][0];                  \
    const char* pB2 = (const char*)&B2s[(buf)][0][0];                  \
    f16x8 a[4], b1[2], b2[2];                                          \
    _Pragma("unroll")                                                  \
    for (int mf = 0; mf < 4; ++mf) a[mf] = *(const f16x8*)(pA + aoff[mf]); \
    _Pragma("unroll")                                                  \
    for (int nf = 0; nf < 2; ++nf) {                                   \
      b1[nf] = *(const f16x8*)(pB1 + boff[nf]);                        \
      b2[nf] = *(const f16x8*)(pB2 + boff[nf]);                        \
    }                                                                  \
    _Pragma("unroll")                                                  \
    for (int mf = 0; mf < 4; ++mf)                                     \
      _Pragma("unroll")                                                \
      for (int nf = 0; nf < 2; ++nf) {                                 \
        acc1[mf][nf] = __builtin_amdgcn_mfma_f32_16x16x32_f16(a[mf], b1[nf], acc1[mf][nf], 0, 0, 0); \
        acc2[mf][nf] = __builtin_amdgcn_mfma_f32_16x16x32_f16(a[mf], b2[nf], acc2[mf][nf], 0, 0, 0); \
      }                                                                \
  } while (0)

  G1_STAGE(0, 0);
  __syncthreads();
  int cur = 0;
  for (int kt = 1; kt < 32; ++kt) {
    G1_STAGE(cur ^ 1, kt);
    G1_COMPUTE(cur);
    __syncthreads();
    cur ^= 1;
  }
  G1_COMPUTE(cur);

  int lk4 = g * 4;
#pragma unroll
  for (int mf = 0; mf < 4; ++mf) {
#pragma unroll
    for (int i = 0; i < 4; ++i) {
      int pl = m0 + wm * 64 + mf * 16 + lk4 + i;
      if (pl >= n_e) continue;
      size_t grow = (size_t)(seg + pl) * FDIM;
#pragma unroll
      for (int nf = 0; nf < 2; ++nf) {
        int col = n0 + wn * 32 + nf * 16 + lr;
        float x1 = acc1[mf][nf][i] + fcbe[col];
        float x2v = acc2[mf][nf][i] + fcbe[2048 + col];
        float gg = x1 * x2v * 0.5f * (1.0f + erff(x2v * 0.70710678118654752f));
        G[grow + col] = (_Float16)gg;
      }
    }
  }
}

// ---------------- GEMM2 (BK=32, 2-way swizzle, prefetch dbuf) ------------
__global__ __launch_bounds__(256) void k_gemm2_out(
    const _Float16* __restrict__ G, const _Float16* __restrict__ Vt,
    const float* __restrict__ ob, const int* __restrict__ offs,
    const int* __restrict__ counts, const int* __restrict__ perm,
    const float* __restrict__ wgt, float* __restrict__ out) {
  int e = blockIdx.y >> 6;
  int m0 = (blockIdx.y & 63) * 128;
  int n_e = counts[e];
  if (m0 >= n_e) return;
  int seg = offs[e];
  int n0 = blockIdx.x * 128;

  __shared__ __align__(16) _Float16 As[2][128][32];   // 16 KB
  __shared__ __align__(16) _Float16 Bs[2][128][32];   // 16 KB

  int tid = threadIdx.x, wid = tid >> 6, lane = tid & 63;
  int wm = wid >> 1, wn = wid & 1;
  const _Float16* Ve = Vt + (size_t)e * (1024ull * 2048ull);
  const float* obe = ob + e * 1024;

  int srow = tid >> 2;
  int scol = ((tid & 3) ^ ((tid >> 3) & 3)) * 8;
  const _Float16* gA[2]; const _Float16* gB[2];
#pragma unroll
  for (int s = 0; s < 2; ++s) {
    int r = min(seg + m0 + s * 64 + srow, T_TOK - 1);
    gA[s] = G + (size_t)r * FDIM + scol;
    gB[s] = Ve + (size_t)(n0 + s * 64 + srow) * FDIM + scol;
  }

  f32x4 acc[4][4];
#pragma unroll
  for (int a = 0; a < 4; ++a)
#pragma unroll
    for (int b = 0; b < 4; ++b) acc[a][b] = (f32x4){0.f, 0.f, 0.f, 0.f};

  int lr = lane & 15, g = lane >> 4;
  int aoff[4], boff[4];
#pragma unroll
  for (int mf = 0; mf < 4; ++mf) {
    int r = wm * 64 + mf * 16 + lr;
    aoff[mf] = r * 64 + ((g ^ ((r >> 1) & 3)) * 16);
  }
#pragma unroll
  for (int nf = 0; nf < 4; ++nf) {
    int r = wn * 64 + nf * 16 + lr;
    boff[nf] = r * 64 + ((g ^ ((r >> 1) & 3)) * 16);
  }

#define G2_STAGE(buf, kt)                                              \
  do {                                                                 \
    int k0_ = (kt) * 32;                                               \
    gl_lds16(gA[0] + k0_, &As[(buf)][0][0] + tid * 8);                 \
    gl_lds16(gA[1] + k0_, &As[(buf)][0][0] + 2048 + tid * 8);          \
    gl_lds16(gB[0] + k0_, &Bs[(buf)][0][0] + tid * 8);                 \
    gl_lds16(gB[1] + k0_, &Bs[(buf)][0][0] + 2048 + tid * 8);          \
  } while (0)

#define G2_COMPUTE(buf)                                                \
  do {                                                                 \
    const char* pA = (const char*)&As[(buf)][0][0];                    \
    const char* pB = (const char*)&Bs[(buf)][0][0];                    \
    f16x8 a[4], b[4];                                                  \
    _Pragma("unroll")                                                  \
    for (int mf = 0; mf < 4; ++mf) a[mf] = *(const f16x8*)(pA + aoff[mf]); \
    _Pragma("unroll")                                                  \
    for (int nf = 0; nf < 4; ++nf) b[nf] = *(const f16x8*)(pB + boff[nf]); \
    _Pragma("unroll")                                                  \
    for (int mf = 0; mf < 4; ++mf)                                     \
      _Pragma("unroll")                                                \
      for (int nf = 0; nf < 4; ++nf)                                   \
        acc[mf][nf] = __builtin_amdgcn_mfma_f32_16x16x32_f16(a[mf], b[nf], acc[mf][nf], 0, 0, 0); \
  } while (0)

  G2_STAGE(0, 0);
  __syncthreads();
  int cur = 0;
  for (int kt = 1; kt < 64; ++kt) {
    G2_STAGE(cur ^ 1, kt);
    G2_COMPUTE(cur);
    __syncthreads();
    cur ^= 1;
  }
  G2_COMPUTE(cur);

  int lk4 = g * 4;
#pragma unroll
  for (int mf = 0; mf < 4; ++mf) {
#pragma unroll
    for (int i = 0; i < 4; ++i) {
      int pl = m0 + wm * 64 + mf * 16 + lk4 + i;
      if (pl >= n_e) continue;
      int p = seg + pl;
      int t = perm[p];
      float wv = wgt[t];
      float* orow = out + (size_t)t * DDIM;
#pragma unroll
      for (int nf = 0; nf < 4; ++nf) {
        int col = n0 + wn * 64 + nf * 16 + lr;
        orow[col] = (acc[mf][nf][i] + obe[col]) * wv;
      }
    }
  }
}

extern "C" void kernel_launch(void* const* d_in, const int* in_sizes, int n_in,
                              void* d_out, int out_size, void* d_ws, size_t ws_size,
                              hipStream_t stream) {
  const float* x   = (const float*)d_in[0];
  const float* gW  = (const float*)d_in[1];
  const float* gb  = (const float*)d_in[2];
  const float* fcW = (const float*)d_in[3];
  const float* fcb = (const float*)d_in[4];
  const float* oW  = (const float*)d_in[5];
  const float* ob  = (const float*)d_in[6];
  float* out = (float*)d_out;

  char* p = (char*)d_ws;
  _Float16* fcWt  = (_Float16*)p; p += (size_t)NEXP * 4096 * 1024 * 2;
  _Float16* outWt = (_Float16*)p; p += (size_t)NEXP * 1024 * 2048 * 2;
  _Float16* Xh    = (_Float16*)p; p += (size_t)T_TOK * DDIM * 2;
  _Float16* G     = (_Float16*)p; p += (size_t)T_TOK * FDIM * 2;
  int*   idx     = (int*)p;   p += T_TOK * 4;
  float* wgt     = (float*)p; p += T_TOK * 4;
  int*   perm    = (int*)p;   p += T_TOK * 4;
  int*   counts  = (int*)p;   p += 64;
  int*   offs    = (int*)p;   p += 64;

  k_gate<<<T_TOK / 8, 256, 0, stream>>>(x, gW, gb, idx, wgt, Xh);
  k_route<<<1, 1024, 0, stream>>>(idx, wgt, perm, counts, offs,
                                  out + (size_t)T_TOK * DDIM);
  k_transpose_cvt<<<dim3(4096 / 32, 1024 / 32, NEXP), 256, 0, stream>>>(fcW, fcWt, 1024, 4096);
  k_transpose_cvt<<<dim3(1024 / 32, 2048 / 32, NEXP), 256, 0, stream>>>(oW, outWt, 2048, 1024);
  k_gemm1_glu<<<dim3(2048 / 64, NEXP * 64), 256, 0, stream>>>(Xh, fcWt, fcb, offs, counts, perm, G);
  k_gemm2_out<<<dim3(1024 / 128, NEXP * 64), 256, 0, stream>>>(G, outWt, ob, offs, counts, perm, wgt, out);
}

// Round 7
// 311.886 us; speedup vs baseline: 1.0552x; 1.0160x over previous
//
#include <hip/hip_runtime.h>
#include <cstdint>
#include <cstddef>

#define T_TOK 8192
#define DDIM 1024
#define FDIM 2048
#define NEXP 8

typedef _Float16 f16x8 __attribute__((ext_vector_type(8)));
typedef _Float16 f16x4 __attribute__((ext_vector_type(4)));
typedef float f32x4 __attribute__((ext_vector_type(4)));

__device__ __forceinline__ void gl_lds16(const void* g, void* s) {
  __builtin_amdgcn_global_load_lds(
      (const __attribute__((address_space(1))) void*)g,
      (__attribute__((address_space(3))) void*)s, 16, 0, 0);
}

// Abramowitz-Stegun 7.1.26, |err| <= 1.5e-7
__device__ __forceinline__ float fast_erf(float x) {
  float ax = __builtin_fabsf(x);
  float t = __builtin_amdgcn_rcpf(1.0f + 0.3275911f * ax);
  float y = t * (0.254829592f +
           t * (-0.284496736f +
           t * (1.421413741f +
           t * (-1.453152027f +
           t * 1.061405429f))));
  float r = 1.0f - y * __expf(-ax * ax);
  return __builtin_copysignf(r, x);
}

// ---------------- gating (fp64 accumulate, no atomics) + fp16 convert ----
__global__ __launch_bounds__(256) void k_gate(
    const float* __restrict__ x, const float* __restrict__ gW,
    const float* __restrict__ gb, int* __restrict__ idx,
    float* __restrict__ wgt, _Float16* __restrict__ Xh) {
  int wid = threadIdx.x >> 6, lane = threadIdx.x & 63;
  int wave = blockIdx.x * 4 + wid;
  int t0 = wave * 2;

  double acc[2][NEXP];
#pragma unroll
  for (int tk = 0; tk < 2; ++tk)
#pragma unroll
    for (int e = 0; e < NEXP; ++e) acc[tk][e] = 0.0;

#pragma unroll
  for (int ch = 0; ch < 4; ++ch) {
    int dbase = ch * 256 + 4 * lane;
    const f32x4* wp = (const f32x4*)(gW + (size_t)dbase * NEXP);
    f32x4 wv[8];
#pragma unroll
    for (int i = 0; i < 8; ++i) wv[i] = wp[i];
#pragma unroll
    for (int tk = 0; tk < 2; ++tk) {
      f32x4 xv = *(const f32x4*)(x + (size_t)(t0 + tk) * DDIM + dbase);
      f16x4 h = { (_Float16)xv[0], (_Float16)xv[1], (_Float16)xv[2], (_Float16)xv[3] };
      *(f16x4*)(Xh + (size_t)(t0 + tk) * DDIM + dbase) = h;
#pragma unroll
      for (int j = 0; j < 4; ++j) {
        double xd = (double)xv[j];
#pragma unroll
        for (int e = 0; e < NEXP; ++e)
          acc[tk][e] += xd * (double)wv[2 * j + (e >> 2)][e & 3];
      }
    }
  }

#pragma unroll
  for (int off = 32; off > 0; off >>= 1) {
#pragma unroll
    for (int tk = 0; tk < 2; ++tk)
#pragma unroll
      for (int e = 0; e < NEXP; ++e)
        acc[tk][e] += __shfl_xor(acc[tk][e], off, 64);
  }
  if (lane == 0) {
#pragma unroll
    for (int tk = 0; tk < 2; ++tk) {
      double mx = -1e300; int am = 0;
#pragma unroll
      for (int e = 0; e < NEXP; ++e) {
        acc[tk][e] += (double)gb[e];
        if (acc[tk][e] > mx) { mx = acc[tk][e]; am = e; }
      }
      double s = 0.0;
#pragma unroll
      for (int e = 0; e < NEXP; ++e) s += exp(acc[tk][e] - mx);
      idx[t0 + tk] = am;
      wgt[t0 + tk] = (float)(1.0 / s);
    }
  }
}

// ---------------- routing: counts/offsets/loss + stable rank scatter ------
__global__ __launch_bounds__(1024) void k_route(
    const int* __restrict__ idx, const float* __restrict__ wgt,
    int* __restrict__ perm, int* __restrict__ counts_out,
    int* __restrict__ offs_out, float* __restrict__ loss_out) {
  __shared__ int cnt_ws[16][NEXP];
  __shared__ float sc_ws[16][NEXP];
  __shared__ int wprefix[16][NEXP];
  __shared__ int base[NEXP];

  int tid = threadIdx.x, w = tid >> 6, lane = tid & 63;

  int c_e[NEXP];
  float s_e[NEXP];
#pragma unroll
  for (int e = 0; e < NEXP; ++e) { c_e[e] = 0; s_e[e] = 0.f; }
  for (int c = 0; c < 8; ++c) {
    int t = c * 1024 + tid;
    int my = idx[t];
    float mw = wgt[t];
#pragma unroll
    for (int e = 0; e < NEXP; ++e) {
      unsigned long long m = __ballot(my == e);
      if (lane == 0) c_e[e] += (int)__popcll(m);
      s_e[e] += (my == e) ? mw : 0.f;
    }
  }
#pragma unroll
  for (int off = 32; off > 0; off >>= 1) {
#pragma unroll
    for (int e = 0; e < NEXP; ++e) s_e[e] += __shfl_xor(s_e[e], off, 64);
  }
  if (lane == 0) {
#pragma unroll
    for (int e = 0; e < NEXP; ++e) { cnt_ws[w][e] = c_e[e]; sc_ws[w][e] = s_e[e]; }
  }
  __syncthreads();
  if (tid == 0) {
    int tot[NEXP]; float sct[NEXP];
#pragma unroll
    for (int e = 0; e < NEXP; ++e) { tot[e] = 0; sct[e] = 0.f; }
    for (int ww = 0; ww < 16; ++ww)
#pragma unroll
      for (int e = 0; e < NEXP; ++e) { tot[e] += cnt_ws[ww][e]; sct[e] += sc_ws[ww][e]; }
    int off = 0; float loss = 0.f;
#pragma unroll
    for (int e = 0; e < NEXP; ++e) {
      offs_out[e] = off; counts_out[e] = tot[e];
      base[e] = off;
      off += tot[e];
      float usage = sct[e] / ((float)tot[e] + 1e-8f);
      float d = usage - (1.0f / NEXP);
      loss += d * d;
    }
    loss_out[0] = loss;
  }
  __syncthreads();

  unsigned long long lt_mask = ((unsigned long long)1 << lane) - 1ull;
  for (int c = 0; c < 8; ++c) {
    int t = c * 1024 + tid;
    int my = idx[t];
    int rank_w = 0;
    int wcnt[NEXP];
#pragma unroll
    for (int e = 0; e < NEXP; ++e) {
      unsigned long long m = __ballot(my == e);
      if (my == e) rank_w = (int)__popcll(m & lt_mask);
      wcnt[e] = (int)__popcll(m);
    }
    if (lane == 0) {
#pragma unroll
      for (int e = 0; e < NEXP; ++e) cnt_ws[w][e] = wcnt[e];
    }
    __syncthreads();
    if (tid < 128) {
      int ww = tid >> 3, e = tid & 7;
      int p = 0;
      for (int w2 = 0; w2 < 16; ++w2) if (w2 < ww) p += cnt_ws[w2][e];
      wprefix[ww][e] = p;
    }
    __syncthreads();
    int pos = base[my] + wprefix[w][my] + rank_w;
    perm[pos] = t;
    __syncthreads();
    if (tid < 8) base[tid] += wprefix[15][tid] + cnt_ws[15][tid];
    __syncthreads();
  }
}

// ---------------- transpose + fp32->fp16 convert ----------------
__global__ __launch_bounds__(256) void k_transpose_cvt(
    const float* __restrict__ src, _Float16* __restrict__ dst, int R, int C) {
  __shared__ _Float16 tile[32][33];
  int tx = threadIdx.x & 31, ty = threadIdx.x >> 5;
  size_t base = (size_t)blockIdx.z * (size_t)R * (size_t)C;
  int c0 = blockIdx.x * 32, r0 = blockIdx.y * 32;
  const float* s = src + base;
  _Float16* d = dst + base;
#pragma unroll
  for (int i = 0; i < 32; i += 8)
    tile[ty + i][tx] = (_Float16)s[(size_t)(r0 + ty + i) * C + c0 + tx];
  __syncthreads();
#pragma unroll
  for (int i = 0; i < 32; i += 8)
    d[(size_t)(c0 + ty + i) * R + r0 + tx] = tile[tx][ty + i];
}

// ---------------- GEMM1 + GLU (128x128, BK=32, swizzle, dbuf, XCD) -------
// grid: x = 16 (n-panels of 128), y = 128 (e*16 + mi), 256 thr
__global__ __launch_bounds__(256, 2) void k_gemm1_glu(
    const _Float16* __restrict__ Xh, const _Float16* __restrict__ Wt,
    const float* __restrict__ fcb, const int* __restrict__ offs,
    const int* __restrict__ counts, const int* __restrict__ perm,
    _Float16* __restrict__ G) {
  // bijective XCD swizzle over nwg = 2048
  int orig = blockIdx.y * 16 + blockIdx.x;
  int swz = (orig & 7) * 256 + (orig >> 3);
  int mx = swz & 15, my = swz >> 4;
  int e = my >> 4;
  int m0 = (my & 15) * 128;
  int n_e = counts[e];
  if (m0 >= n_e) return;
  int seg = offs[e];
  int n0 = mx * 128;

  __shared__ __align__(16) _Float16 As[2][128][32];    // 16 KB
  __shared__ __align__(16) _Float16 B1s[2][128][32];   // 16 KB
  __shared__ __align__(16) _Float16 B2s[2][128][32];   // 16 KB

  int tid = threadIdx.x, wid = tid >> 6, lane = tid & 63;
  int wm = wid >> 1, wn = wid & 1;

  const _Float16* We = Wt + (size_t)e * (4096ull * 1024ull);
  const float* fcbe = fcb + e * 4096;

  int srow = tid >> 2;
  int scol = ((tid & 3) ^ ((tid >> 3) & 3)) * 8;
  const _Float16* gA[2]; const _Float16* gB1[2]; const _Float16* gB2[2];
#pragma unroll
  for (int s = 0; s < 2; ++s) {
    int rowp = min(seg + m0 + s * 64 + srow, T_TOK - 1);
    gA[s]  = Xh + (size_t)perm[rowp] * DDIM + scol;
    gB1[s] = We + (size_t)(n0 + s * 64 + srow) * DDIM + scol;
    gB2[s] = We + (size_t)(2048 + n0 + s * 64 + srow) * DDIM + scol;
  }

  f32x4 acc1[4][4], acc2[4][4];
#pragma unroll
  for (int a = 0; a < 4; ++a)
#pragma unroll
    for (int b = 0; b < 4; ++b) {
      acc1[a][b] = (f32x4){0.f, 0.f, 0.f, 0.f};
      acc2[a][b] = (f32x4){0.f, 0.f, 0.f, 0.f};
    }

  int lr = lane & 15, g = lane >> 4;
  int aoff[4], boff[4];
#pragma unroll
  for (int mf = 0; mf < 4; ++mf) {
    int r = wm * 64 + mf * 16 + lr;
    aoff[mf] = r * 64 + ((g ^ ((r >> 1) & 3)) * 16);
  }
#pragma unroll
  for (int nf = 0; nf < 4; ++nf) {
    int r = wn * 64 + nf * 16 + lr;
    boff[nf] = r * 64 + ((g ^ ((r >> 1) & 3)) * 16);
  }

#define G1_STAGE(buf, kt)                                              \
  do {                                                                 \
    int k0_ = (kt) * 32;                                               \
    gl_lds16(gA[0] + k0_, &As[(buf)][0][0] + tid * 8);                 \
    gl_lds16(gA[1] + k0_, &As[(buf)][0][0] + 2048 + tid * 8);          \
    gl_lds16(gB1[0] + k0_, &B1s[(buf)][0][0] + tid * 8);               \
    gl_lds16(gB1[1] + k0_, &B1s[(buf)][0][0] + 2048 + tid * 8);        \
    gl_lds16(gB2[0] + k0_, &B2s[(buf)][0][0] + tid * 8);               \
    gl_lds16(gB2[1] + k0_, &B2s[(buf)][0][0] + 2048 + tid * 8);        \
  } while (0)

#define G1_COMPUTE(buf)                                                \
  do {                                                                 \
    const char* pA = (const char*)&As[(buf)][0][0];                    \
    const char* pB1 = (const char*)&B1s[(buf)][0][0];                  \
    const char* pB2 = (const char*)&B2s[(buf)][0][0];                  \
    f16x8 a[4], b1[4], b2[4];                                          \
    _Pragma("unroll")                                                  \
    for (int mf = 0; mf < 4; ++mf) a[mf] = *(const f16x8*)(pA + aoff[mf]); \
    _Pragma("unroll")                                                  \
    for (int nf = 0; nf < 4; ++nf) {                                   \
      b1[nf] = *(const f16x8*)(pB1 + boff[nf]);                        \
      b2[nf] = *(const f16x8*)(pB2 + boff[nf]);                        \
    }                                                                  \
    _Pragma("unroll")                                                  \
    for (int mf = 0; mf < 4; ++mf)                                     \
      _Pragma("unroll")                                                \
      for (int nf = 0; nf < 4; ++nf) {                                 \
        acc1[mf][nf] = __builtin_amdgcn_mfma_f32_16x16x32_f16(a[mf], b1[nf], acc1[mf][nf], 0, 0, 0); \
        acc2[mf][nf] = __builtin_amdgcn_mfma_f32_16x16x32_f16(a[mf], b2[nf], acc2[mf][nf], 0, 0, 0); \
      }                                                                \
  } while (0)

  G1_STAGE(0, 0);
  __syncthreads();
  int cur = 0;
  for (int kt = 1; kt < 32; ++kt) {
    G1_STAGE(cur ^ 1, kt);
    G1_COMPUTE(cur);
    __syncthreads();
    cur ^= 1;
  }
  G1_COMPUTE(cur);

  int lk4 = g * 4;
#pragma unroll
  for (int mf = 0; mf < 4; ++mf) {
#pragma unroll
    for (int i = 0; i < 4; ++i) {
      int pl = m0 + wm * 64 + mf * 16 + lk4 + i;
      if (pl >= n_e) continue;
      size_t grow = (size_t)(seg + pl) * FDIM;
#pragma unroll
      for (int nf = 0; nf < 4; ++nf) {
        int col = n0 + wn * 64 + nf * 16 + lr;
        float x1 = acc1[mf][nf][i] + fcbe[col];
        float x2v = acc2[mf][nf][i] + fcbe[2048 + col];
        float gg = x1 * x2v * 0.5f * (1.0f + fast_erf(x2v * 0.70710678118654752f));
        G[grow + col] = (_Float16)gg;
      }
    }
  }
}

// ---------------- GEMM2 (BK=32, swizzle, dbuf, XCD) ----------------------
// grid: x = 8 (n-panels of 128), y = 128 (e*16 + mi), 256 thr
__global__ __launch_bounds__(256) void k_gemm2_out(
    const _Float16* __restrict__ G, const _Float16* __restrict__ Vt,
    const float* __restrict__ ob, const int* __restrict__ offs,
    const int* __restrict__ counts, const int* __restrict__ perm,
    const float* __restrict__ wgt, float* __restrict__ out) {
  // bijective XCD swizzle over nwg = 1024
  int orig = blockIdx.y * 8 + blockIdx.x;
  int swz = (orig & 7) * 128 + (orig >> 3);
  int mx = swz & 7, my = swz >> 3;
  int e = my >> 4;
  int m0 = (my & 15) * 128;
  int n_e = counts[e];
  if (m0 >= n_e) return;
  int seg = offs[e];
  int n0 = mx * 128;

  __shared__ __align__(16) _Float16 As[2][128][32];   // 16 KB
  __shared__ __align__(16) _Float16 Bs[2][128][32];   // 16 KB

  int tid = threadIdx.x, wid = tid >> 6, lane = tid & 63;
  int wm = wid >> 1, wn = wid & 1;
  const _Float16* Ve = Vt + (size_t)e * (1024ull * 2048ull);
  const float* obe = ob + e * 1024;

  int srow = tid >> 2;
  int scol = ((tid & 3) ^ ((tid >> 3) & 3)) * 8;
  const _Float16* gA[2]; const _Float16* gB[2];
#pragma unroll
  for (int s = 0; s < 2; ++s) {
    int r = min(seg + m0 + s * 64 + srow, T_TOK - 1);
    gA[s] = G + (size_t)r * FDIM + scol;
    gB[s] = Ve + (size_t)(n0 + s * 64 + srow) * FDIM + scol;
  }

  f32x4 acc[4][4];
#pragma unroll
  for (int a = 0; a < 4; ++a)
#pragma unroll
    for (int b = 0; b < 4; ++b) acc[a][b] = (f32x4){0.f, 0.f, 0.f, 0.f};

  int lr = lane & 15, g = lane >> 4;
  int aoff[4], boff[4];
#pragma unroll
  for (int mf = 0; mf < 4; ++mf) {
    int r = wm * 64 + mf * 16 + lr;
    aoff[mf] = r * 64 + ((g ^ ((r >> 1) & 3)) * 16);
  }
#pragma unroll
  for (int nf = 0; nf < 4; ++nf) {
    int r = wn * 64 + nf * 16 + lr;
    boff[nf] = r * 64 + ((g ^ ((r >> 1) & 3)) * 16);
  }

#define G2_STAGE(buf, kt)                                              \
  do {                                                                 \
    int k0_ = (kt) * 32;                                               \
    gl_lds16(gA[0] + k0_, &As[(buf)][0][0] + tid * 8);                 \
    gl_lds16(gA[1] + k0_, &As[(buf)][0][0] + 2048 + tid * 8);          \
    gl_lds16(gB[0] + k0_, &Bs[(buf)][0][0] + tid * 8);                 \
    gl_lds16(gB[1] + k0_, &Bs[(buf)][0][0] + 2048 + tid * 8);          \
  } while (0)

#define G2_COMPUTE(buf)                                                \
  do {                                                                 \
    const char* pA = (const char*)&As[(buf)][0][0];                    \
    const char* pB = (const char*)&Bs[(buf)][0][0];                    \
    f16x8 a[4], b[4];                                                  \
    _Pragma("unroll")                                                  \
    for (int mf = 0; mf < 4; ++mf) a[mf] = *(const f16x8*)(pA + aoff[mf]); \
    _Pragma("unroll")                                                  \
    for (int nf = 0; nf < 4; ++nf) b[nf] = *(const f16x8*)(pB + boff[nf]); \
    _Pragma("unroll")                                                  \
    for (int mf = 0; mf < 4; ++mf)                                     \
      _Pragma("unroll")                                                \
      for (int nf = 0; nf < 4; ++nf)                                   \
        acc[mf][nf] = __builtin_amdgcn_mfma_f32_16x16x32_f16(a[mf], b[nf], acc[mf][nf], 0, 0, 0); \
  } while (0)

  G2_STAGE(0, 0);
  __syncthreads();
  int cur = 0;
  for (int kt = 1; kt < 64; ++kt) {
    G2_STAGE(cur ^ 1, kt);
    G2_COMPUTE(cur);
    __syncthreads();
    cur ^= 1;
  }
  G2_COMPUTE(cur);

  int lk4 = g * 4;
#pragma unroll
  for (int mf = 0; mf < 4; ++mf) {
#pragma unroll
    for (int i = 0; i < 4; ++i) {
      int pl = m0 + wm * 64 + mf * 16 + lk4 + i;
      if (pl >= n_e) continue;
      int p = seg + pl;
      int t = perm[p];
      float wv = wgt[t];
      float* orow = out + (size_t)t * DDIM;
#pragma unroll
      for (int nf = 0; nf < 4; ++nf) {
        int col = n0 + wn * 64 + nf * 16 + lr;
        orow[col] = (acc[mf][nf][i] + obe[col]) * wv;
      }
    }
  }
}

extern "C" void kernel_launch(void* const* d_in, const int* in_sizes, int n_in,
                              void* d_out, int out_size, void* d_ws, size_t ws_size,
                              hipStream_t stream) {
  const float* x   = (const float*)d_in[0];
  const float* gW  = (const float*)d_in[1];
  const float* gb  = (const float*)d_in[2];
  const float* fcW = (const float*)d_in[3];
  const float* fcb = (const float*)d_in[4];
  const float* oW  = (const float*)d_in[5];
  const float* ob  = (const float*)d_in[6];
  float* out = (float*)d_out;

  char* p = (char*)d_ws;
  _Float16* fcWt  = (_Float16*)p; p += (size_t)NEXP * 4096 * 1024 * 2;
  _Float16* outWt = (_Float16*)p; p += (size_t)NEXP * 1024 * 2048 * 2;
  _Float16* Xh    = (_Float16*)p; p += (size_t)T_TOK * DDIM * 2;
  _Float16* G     = (_Float16*)p; p += (size_t)T_TOK * FDIM * 2;
  int*   idx     = (int*)p;   p += T_TOK * 4;
  float* wgt     = (float*)p; p += T_TOK * 4;
  int*   perm    = (int*)p;   p += T_TOK * 4;
  int*   counts  = (int*)p;   p += 64;
  int*   offs    = (int*)p;   p += 64;

  k_gate<<<T_TOK / 8, 256, 0, stream>>>(x, gW, gb, idx, wgt, Xh);
  k_route<<<1, 1024, 0, stream>>>(idx, wgt, perm, counts, offs,
                                  out + (size_t)T_TOK * DDIM);
  k_transpose_cvt<<<dim3(4096 / 32, 1024 / 32, NEXP), 256, 0, stream>>>(fcW, fcWt, 1024, 4096);
  k_transpose_cvt<<<dim3(1024 / 32, 2048 / 32, NEXP), 256, 0, stream>>>(oW, outWt, 2048, 1024);
  k_gemm1_glu<<<dim3(16, 128), 256, 0, stream>>>(Xh, fcWt, fcb, offs, counts, perm, G);
  k_gemm2_out<<<dim3(8, 128), 256, 0, stream>>>(G, outWt, ob, offs, counts, perm, wgt, out);
}

// Round 8
// 276.688 us; speedup vs baseline: 1.1895x; 1.1272x over previous
//
#include <hip/hip_runtime.h>
#include <cstdint>
#include <cstddef>

#define T_TOK 8192
#define DDIM 1024
#define FDIM 2048
#define NEXP 8

typedef _Float16 f16x8 __attribute__((ext_vector_type(8)));
typedef _Float16 f16x4 __attribute__((ext_vector_type(4)));
typedef float f32x4 __attribute__((ext_vector_type(4)));

__device__ __forceinline__ void gl_lds16(const void* g, void* s) {
  __builtin_amdgcn_global_load_lds(
      (const __attribute__((address_space(1))) void*)g,
      (__attribute__((address_space(3))) void*)s, 16, 0, 0);
}

#define WAITVM(n) asm volatile("s_waitcnt vmcnt(" #n ")" ::: "memory")

// Abramowitz-Stegun 7.1.26, |err| <= 1.5e-7
__device__ __forceinline__ float fast_erf(float x) {
  float ax = __builtin_fabsf(x);
  float t = __builtin_amdgcn_rcpf(1.0f + 0.3275911f * ax);
  float y = t * (0.254829592f +
           t * (-0.284496736f +
           t * (1.421413741f +
           t * (-1.453152027f +
           t * 1.061405429f))));
  float r = 1.0f - y * __expf(-ax * ax);
  return __builtin_copysignf(r, x);
}

// ---------------- gating (fp64 accumulate, no atomics) + fp16 convert ----
__global__ __launch_bounds__(256) void k_gate(
    const float* __restrict__ x, const float* __restrict__ gW,
    const float* __restrict__ gb, int* __restrict__ idx,
    float* __restrict__ wgt, _Float16* __restrict__ Xh) {
  int wid = threadIdx.x >> 6, lane = threadIdx.x & 63;
  int wave = blockIdx.x * 4 + wid;
  int t0 = wave * 2;

  double acc[2][NEXP];
#pragma unroll
  for (int tk = 0; tk < 2; ++tk)
#pragma unroll
    for (int e = 0; e < NEXP; ++e) acc[tk][e] = 0.0;

#pragma unroll
  for (int ch = 0; ch < 4; ++ch) {
    int dbase = ch * 256 + 4 * lane;
    const f32x4* wp = (const f32x4*)(gW + (size_t)dbase * NEXP);
    f32x4 wv[8];
#pragma unroll
    for (int i = 0; i < 8; ++i) wv[i] = wp[i];
#pragma unroll
    for (int tk = 0; tk < 2; ++tk) {
      f32x4 xv = *(const f32x4*)(x + (size_t)(t0 + tk) * DDIM + dbase);
      f16x4 h = { (_Float16)xv[0], (_Float16)xv[1], (_Float16)xv[2], (_Float16)xv[3] };
      *(f16x4*)(Xh + (size_t)(t0 + tk) * DDIM + dbase) = h;
#pragma unroll
      for (int j = 0; j < 4; ++j) {
        double xd = (double)xv[j];
#pragma unroll
        for (int e = 0; e < NEXP; ++e)
          acc[tk][e] += xd * (double)wv[2 * j + (e >> 2)][e & 3];
      }
    }
  }

#pragma unroll
  for (int off = 32; off > 0; off >>= 1) {
#pragma unroll
    for (int tk = 0; tk < 2; ++tk)
#pragma unroll
      for (int e = 0; e < NEXP; ++e)
        acc[tk][e] += __shfl_xor(acc[tk][e], off, 64);
  }
  if (lane == 0) {
#pragma unroll
    for (int tk = 0; tk < 2; ++tk) {
      double mx = -1e300; int am = 0;
#pragma unroll
      for (int e = 0; e < NEXP; ++e) {
        acc[tk][e] += (double)gb[e];
        if (acc[tk][e] > mx) { mx = acc[tk][e]; am = e; }
      }
      double s = 0.0;
#pragma unroll
      for (int e = 0; e < NEXP; ++e) s += exp(acc[tk][e] - mx);
      idx[t0 + tk] = am;
      wgt[t0 + tk] = (float)(1.0 / s);
    }
  }
}

// ---------------- routing: counts/offsets/loss + stable rank scatter ------
__global__ __launch_bounds__(1024) void k_route(
    const int* __restrict__ idx, const float* __restrict__ wgt,
    int* __restrict__ perm, int* __restrict__ counts_out,
    int* __restrict__ offs_out, float* __restrict__ loss_out) {
  __shared__ int cnt_ws[16][NEXP];
  __shared__ float sc_ws[16][NEXP];
  __shared__ int wprefix[16][NEXP];
  __shared__ int base[NEXP];

  int tid = threadIdx.x, w = tid >> 6, lane = tid & 63;

  int c_e[NEXP];
  float s_e[NEXP];
#pragma unroll
  for (int e = 0; e < NEXP; ++e) { c_e[e] = 0; s_e[e] = 0.f; }
  for (int c = 0; c < 8; ++c) {
    int t = c * 1024 + tid;
    int my = idx[t];
    float mw = wgt[t];
#pragma unroll
    for (int e = 0; e < NEXP; ++e) {
      unsigned long long m = __ballot(my == e);
      if (lane == 0) c_e[e] += (int)__popcll(m);
      s_e[e] += (my == e) ? mw : 0.f;
    }
  }
#pragma unroll
  for (int off = 32; off > 0; off >>= 1) {
#pragma unroll
    for (int e = 0; e < NEXP; ++e) s_e[e] += __shfl_xor(s_e[e], off, 64);
  }
  if (lane == 0) {
#pragma unroll
    for (int e = 0; e < NEXP; ++e) { cnt_ws[w][e] = c_e[e]; sc_ws[w][e] = s_e[e]; }
  }
  __syncthreads();
  if (tid == 0) {
    int tot[NEXP]; float sct[NEXP];
#pragma unroll
    for (int e = 0; e < NEXP; ++e) { tot[e] = 0; sct[e] = 0.f; }
    for (int ww = 0; ww < 16; ++ww)
#pragma unroll
      for (int e = 0; e < NEXP; ++e) { tot[e] += cnt_ws[ww][e]; sct[e] += sc_ws[ww][e]; }
    int off = 0; float loss = 0.f;
#pragma unroll
    for (int e = 0; e < NEXP; ++e) {
      offs_out[e] = off; counts_out[e] = tot[e];
      base[e] = off;
      off += tot[e];
      float usage = sct[e] / ((float)tot[e] + 1e-8f);
      float d = usage - (1.0f / NEXP);
      loss += d * d;
    }
    loss_out[0] = loss;
  }
  __syncthreads();

  unsigned long long lt_mask = ((unsigned long long)1 << lane) - 1ull;
  for (int c = 0; c < 8; ++c) {
    int t = c * 1024 + tid;
    int my = idx[t];
    int rank_w = 0;
    int wcnt[NEXP];
#pragma unroll
    for (int e = 0; e < NEXP; ++e) {
      unsigned long long m = __ballot(my == e);
      if (my == e) rank_w = (int)__popcll(m & lt_mask);
      wcnt[e] = (int)__popcll(m);
    }
    if (lane == 0) {
#pragma unroll
      for (int e = 0; e < NEXP; ++e) cnt_ws[w][e] = wcnt[e];
    }
    __syncthreads();
    if (tid < 128) {
      int ww = tid >> 3, e = tid & 7;
      int p = 0;
      for (int w2 = 0; w2 < 16; ++w2) if (w2 < ww) p += cnt_ws[w2][e];
      wprefix[ww][e] = p;
    }
    __syncthreads();
    int pos = base[my] + wprefix[w][my] + rank_w;
    perm[pos] = t;
    __syncthreads();
    if (tid < 8) base[tid] += wprefix[15][tid] + cnt_ws[15][tid];
    __syncthreads();
  }
}

// ---------------- transpose + fp32->fp16 convert ----------------
__global__ __launch_bounds__(256) void k_transpose_cvt(
    const float* __restrict__ src, _Float16* __restrict__ dst, int R, int C) {
  __shared__ _Float16 tile[32][33];
  int tx = threadIdx.x & 31, ty = threadIdx.x >> 5;
  size_t base = (size_t)blockIdx.z * (size_t)R * (size_t)C;
  int c0 = blockIdx.x * 32, r0 = blockIdx.y * 32;
  const float* s = src + base;
  _Float16* d = dst + base;
#pragma unroll
  for (int i = 0; i < 32; i += 8)
    tile[ty + i][tx] = (_Float16)s[(size_t)(r0 + ty + i) * C + c0 + tx];
  __syncthreads();
#pragma unroll
  for (int i = 0; i < 32; i += 8)
    d[(size_t)(c0 + ty + i) * R + r0 + tx] = tile[tx][ty + i];
}

// ---------------- GEMM1 + GLU (128x(64+64), BK=32, 3-buf, counted vmcnt) -
// grid: x = 32 (n-panels of 64), y = 128 (e*16 + mi), 256 thr
__global__ __launch_bounds__(256) void k_gemm1_glu(
    const _Float16* __restrict__ Xh, const _Float16* __restrict__ Wt,
    const float* __restrict__ fcb, const int* __restrict__ offs,
    const int* __restrict__ counts, const int* __restrict__ perm,
    _Float16* __restrict__ G) {
  // bijective XCD swizzle over nwg = 4096
  int orig = blockIdx.y * 32 + blockIdx.x;
  int swz = (orig & 7) * 512 + (orig >> 3);
  int mx = swz & 31, my = swz >> 5;
  int e = my >> 4;
  int m0 = (my & 15) * 128;
  int n_e = counts[e];
  if (m0 >= n_e) return;
  int seg = offs[e];
  int n0 = mx * 64;

  __shared__ __align__(16) _Float16 As[3][128][32];    // 24 KB
  __shared__ __align__(16) _Float16 B1s[3][64][32];    // 12 KB
  __shared__ __align__(16) _Float16 B2s[3][64][32];    // 12 KB

  int tid = threadIdx.x, wid = tid >> 6, lane = tid & 63;
  int wm = wid >> 1, wn = wid & 1;

  const _Float16* We = Wt + (size_t)e * (4096ull * 1024ull);
  const float* fcbe = fcb + e * 4096;

  // staging map: row = tid>>2, dest chunk = tid&3,
  // source chunk = (tid&3) ^ ((row>>1)&3)
  int srow = tid >> 2;
  int scol = ((tid & 3) ^ ((tid >> 3) & 3)) * 8;
  const _Float16* gA[2];
#pragma unroll
  for (int s = 0; s < 2; ++s) {
    int rowp = min(seg + m0 + s * 64 + srow, T_TOK - 1);
    gA[s] = Xh + (size_t)perm[rowp] * DDIM + scol;
  }
  const _Float16* gB1 = We + (size_t)(n0 + srow) * DDIM + scol;
  const _Float16* gB2 = We + (size_t)(2048 + n0 + srow) * DDIM + scol;

  f32x4 acc1[4][2], acc2[4][2];
#pragma unroll
  for (int a = 0; a < 4; ++a)
#pragma unroll
    for (int b = 0; b < 2; ++b) {
      acc1[a][b] = (f32x4){0.f, 0.f, 0.f, 0.f};
      acc2[a][b] = (f32x4){0.f, 0.f, 0.f, 0.f};
    }

  int lr = lane & 15, g = lane >> 4;
  int aoff[4], boff[2];
#pragma unroll
  for (int mf = 0; mf < 4; ++mf) {
    int r = wm * 64 + mf * 16 + lr;
    aoff[mf] = r * 64 + ((g ^ ((r >> 1) & 3)) * 16);
  }
#pragma unroll
  for (int nf = 0; nf < 2; ++nf) {
    int r = wn * 32 + nf * 16 + lr;
    boff[nf] = r * 64 + ((g ^ ((r >> 1) & 3)) * 16);
  }

#define G1_STAGE(dA, dB1, dB2, kt)                                     \
  do {                                                                 \
    int k0_ = (kt) * 32;                                               \
    gl_lds16(gA[0] + k0_, (dA) + tid * 8);                             \
    gl_lds16(gA[1] + k0_, (dA) + 2048 + tid * 8);                      \
    gl_lds16(gB1 + k0_, (dB1) + tid * 8);                              \
    gl_lds16(gB2 + k0_, (dB2) + tid * 8);                              \
  } while (0)

#define G1_COMPUTE(pAv, pB1v, pB2v)                                    \
  do {                                                                 \
    const char* pA = (const char*)(pAv);                               \
    const char* pB1 = (const char*)(pB1v);                             \
    const char* pB2 = (const char*)(pB2v);                             \
    f16x8 a[4], b1[2], b2[2];                                          \
    _Pragma("unroll")                                                  \
    for (int mf = 0; mf < 4; ++mf) a[mf] = *(const f16x8*)(pA + aoff[mf]); \
    _Pragma("unroll")                                                  \
    for (int nf = 0; nf < 2; ++nf) {                                   \
      b1[nf] = *(const f16x8*)(pB1 + boff[nf]);                        \
      b2[nf] = *(const f16x8*)(pB2 + boff[nf]);                        \
    }                                                                  \
    _Pragma("unroll")                                                  \
    for (int mf = 0; mf < 4; ++mf)                                     \
      _Pragma("unroll")                                                \
      for (int nf = 0; nf < 2; ++nf) {                                 \
        acc1[mf][nf] = __builtin_amdgcn_mfma_f32_16x16x32_f16(a[mf], b1[nf], acc1[mf][nf], 0, 0, 0); \
        acc2[mf][nf] = __builtin_amdgcn_mfma_f32_16x16x32_f16(a[mf], b2[nf], acc2[mf][nf], 0, 0, 0); \
      }                                                                \
  } while (0)

  // rotating buffer pointers: c = tile kt, n = kt+1, f = stage target kt+2
  _Float16 *cA = &As[0][0][0], *nA = &As[1][0][0], *fA = &As[2][0][0];
  _Float16 *cB1 = &B1s[0][0][0], *nB1 = &B1s[1][0][0], *fB1 = &B1s[2][0][0];
  _Float16 *cB2 = &B2s[0][0][0], *nB2 = &B2s[1][0][0], *fB2 = &B2s[2][0][0];

  G1_STAGE(cA, cB1, cB2, 0);
  G1_STAGE(nA, nB1, nB2, 1);

  for (int kt = 0; kt < 32; ++kt) {
    if (kt < 30) {
      G1_STAGE(fA, fB1, fB2, kt + 2);
      WAITVM(8);
    } else if (kt == 30) {
      WAITVM(4);
    } else {
      WAITVM(0);
    }
    __builtin_amdgcn_s_barrier();
    __builtin_amdgcn_sched_barrier(0);
    G1_COMPUTE(cA, cB1, cB2);
    __builtin_amdgcn_s_barrier();
    _Float16* t;
    t = cA; cA = nA; nA = fA; fA = t;
    t = cB1; cB1 = nB1; nB1 = fB1; fB1 = t;
    t = cB2; cB2 = nB2; nB2 = fB2; fB2 = t;
  }

  int lk4 = g * 4;
#pragma unroll
  for (int mf = 0; mf < 4; ++mf) {
#pragma unroll
    for (int i = 0; i < 4; ++i) {
      int pl = m0 + wm * 64 + mf * 16 + lk4 + i;
      if (pl >= n_e) continue;
      size_t grow = (size_t)(seg + pl) * FDIM;
#pragma unroll
      for (int nf = 0; nf < 2; ++nf) {
        int col = n0 + wn * 32 + nf * 16 + lr;
        float x1 = acc1[mf][nf][i] + fcbe[col];
        float x2v = acc2[mf][nf][i] + fcbe[2048 + col];
        float gg = x1 * x2v * 0.5f * (1.0f + fast_erf(x2v * 0.70710678118654752f));
        G[grow + col] = (_Float16)gg;
      }
    }
  }
}

// ---------------- GEMM2 (128x128, BK=32, 3-buf, counted vmcnt) -----------
// grid: x = 8 (n-panels of 128), y = 128 (e*16 + mi), 256 thr
__global__ __launch_bounds__(256) void k_gemm2_out(
    const _Float16* __restrict__ G, const _Float16* __restrict__ Vt,
    const float* __restrict__ ob, const int* __restrict__ offs,
    const int* __restrict__ counts, const int* __restrict__ perm,
    const float* __restrict__ wgt, float* __restrict__ out) {
  // bijective XCD swizzle over nwg = 1024
  int orig = blockIdx.y * 8 + blockIdx.x;
  int swz = (orig & 7) * 128 + (orig >> 3);
  int mx = swz & 7, my = swz >> 3;
  int e = my >> 4;
  int m0 = (my & 15) * 128;
  int n_e = counts[e];
  if (m0 >= n_e) return;
  int seg = offs[e];
  int n0 = mx * 128;

  __shared__ __align__(16) _Float16 As[3][128][32];   // 24 KB
  __shared__ __align__(16) _Float16 Bs[3][128][32];   // 24 KB

  int tid = threadIdx.x, wid = tid >> 6, lane = tid & 63;
  int wm = wid >> 1, wn = wid & 1;
  const _Float16* Ve = Vt + (size_t)e * (1024ull * 2048ull);
  const float* obe = ob + e * 1024;

  int srow = tid >> 2;
  int scol = ((tid & 3) ^ ((tid >> 3) & 3)) * 8;
  const _Float16* gA[2]; const _Float16* gB[2];
#pragma unroll
  for (int s = 0; s < 2; ++s) {
    int r = min(seg + m0 + s * 64 + srow, T_TOK - 1);
    gA[s] = G + (size_t)r * FDIM + scol;
    gB[s] = Ve + (size_t)(n0 + s * 64 + srow) * FDIM + scol;
  }

  f32x4 acc[4][4];
#pragma unroll
  for (int a = 0; a < 4; ++a)
#pragma unroll
    for (int b = 0; b < 4; ++b) acc[a][b] = (f32x4){0.f, 0.f, 0.f, 0.f};

  int lr = lane & 15, g = lane >> 4;
  int aoff[4], boff[4];
#pragma unroll
  for (int mf = 0; mf < 4; ++mf) {
    int r = wm * 64 + mf * 16 + lr;
    aoff[mf] = r * 64 + ((g ^ ((r >> 1) & 3)) * 16);
  }
#pragma unroll
  for (int nf = 0; nf < 4; ++nf) {
    int r = wn * 64 + nf * 16 + lr;
    boff[nf] = r * 64 + ((g ^ ((r >> 1) & 3)) * 16);
  }

#define G2_STAGE(dA, dB, kt)                                           \
  do {                                                                 \
    int k0_ = (kt) * 32;                                               \
    gl_lds16(gA[0] + k0_, (dA) + tid * 8);                             \
    gl_lds16(gA[1] + k0_, (dA) + 2048 + tid * 8);                      \
    gl_lds16(gB[0] + k0_, (dB) + tid * 8);                             \
    gl_lds16(gB[1] + k0_, (dB) + 2048 + tid * 8);                      \
  } while (0)

#define G2_COMPUTE(pAv, pBv)                                           \
  do {                                                                 \
    const char* pA = (const char*)(pAv);                               \
    const char* pB = (const char*)(pBv);                               \
    f16x8 a[4], b[4];                                                  \
    _Pragma("unroll")                                                  \
    for (int mf = 0; mf < 4; ++mf) a[mf] = *(const f16x8*)(pA + aoff[mf]); \
    _Pragma("unroll")                                                  \
    for (int nf = 0; nf < 4; ++nf) b[nf] = *(const f16x8*)(pB + boff[nf]); \
    _Pragma("unroll")                                                  \
    for (int mf = 0; mf < 4; ++mf)                                     \
      _Pragma("unroll")                                                \
      for (int nf = 0; nf < 4; ++nf)                                   \
        acc[mf][nf] = __builtin_amdgcn_mfma_f32_16x16x32_f16(a[mf], b[nf], acc[mf][nf], 0, 0, 0); \
  } while (0)

  _Float16 *cA = &As[0][0][0], *nA = &As[1][0][0], *fA = &As[2][0][0];
  _Float16 *cB = &Bs[0][0][0], *nB = &Bs[1][0][0], *fB = &Bs[2][0][0];

  G2_STAGE(cA, cB, 0);
  G2_STAGE(nA, nB, 1);

  for (int kt = 0; kt < 64; ++kt) {
    if (kt < 62) {
      G2_STAGE(fA, fB, kt + 2);
      WAITVM(8);
    } else if (kt == 62) {
      WAITVM(4);
    } else {
      WAITVM(0);
    }
    __builtin_amdgcn_s_barrier();
    __builtin_amdgcn_sched_barrier(0);
    G2_COMPUTE(cA, cB);
    __builtin_amdgcn_s_barrier();
    _Float16* t;
    t = cA; cA = nA; nA = fA; fA = t;
    t = cB; cB = nB; nB = fB; fB = t;
  }

  int lk4 = g * 4;
#pragma unroll
  for (int mf = 0; mf < 4; ++mf) {
#pragma unroll
    for (int i = 0; i < 4; ++i) {
      int pl = m0 + wm * 64 + mf * 16 + lk4 + i;
      if (pl >= n_e) continue;
      int p = seg + pl;
      int t = perm[p];
      float wv = wgt[t];
      float* orow = out + (size_t)t * DDIM;
#pragma unroll
      for (int nf = 0; nf < 4; ++nf) {
        int col = n0 + wn * 64 + nf * 16 + lr;
        orow[col] = (acc[mf][nf][i] + obe[col]) * wv;
      }
    }
  }
}

extern "C" void kernel_launch(void* const* d_in, const int* in_sizes, int n_in,
                              void* d_out, int out_size, void* d_ws, size_t ws_size,
                              hipStream_t stream) {
  const float* x   = (const float*)d_in[0];
  const float* gW  = (const float*)d_in[1];
  const float* gb  = (const float*)d_in[2];
  const float* fcW = (const float*)d_in[3];
  const float* fcb = (const float*)d_in[4];
  const float* oW  = (const float*)d_in[5];
  const float* ob  = (const float*)d_in[6];
  float* out = (float*)d_out;

  char* p = (char*)d_ws;
  _Float16* fcWt  = (_Float16*)p; p += (size_t)NEXP * 4096 * 1024 * 2;
  _Float16* outWt = (_Float16*)p; p += (size_t)NEXP * 1024 * 2048 * 2;
  _Float16* Xh    = (_Float16*)p; p += (size_t)T_TOK * DDIM * 2;
  _Float16* G     = (_Float16*)p; p += (size_t)T_TOK * FDIM * 2;
  int*   idx     = (int*)p;   p += T_TOK * 4;
  float* wgt     = (float*)p; p += T_TOK * 4;
  int*   perm    = (int*)p;   p += T_TOK * 4;
  int*   counts  = (int*)p;   p += 64;
  int*   offs    = (int*)p;   p += 64;

  k_gate<<<T_TOK / 8, 256, 0, stream>>>(x, gW, gb, idx, wgt, Xh);
  k_route<<<1, 1024, 0, stream>>>(idx, wgt, perm, counts, offs,
                                  out + (size_t)T_TOK * DDIM);
  k_transpose_cvt<<<dim3(4096 / 32, 1024 / 32, NEXP), 256, 0, stream>>>(fcW, fcWt, 1024, 4096);
  k_transpose_cvt<<<dim3(1024 / 32, 2048 / 32, NEXP), 256, 0, stream>>>(oW, outWt, 2048, 1024);
  k_gemm1_glu<<<dim3(32, 128), 256, 0, stream>>>(Xh, fcWt, fcb, offs, counts, perm, G);
  k_gemm2_out<<<dim3(8, 128), 256, 0, stream>>>(G, outWt, ob, offs, counts, perm, wgt, out);
}